// Round 3
// baseline (431.892 us; speedup 1.0000x reference)
//
#include <hip/hip_runtime.h>

// y = relu(x @ (w1*m)^T + b1) @ (w2*m^T)^T + b2
// R3: occupancy-first. 512-thread blocks (8 waves), MT=64 rows; wave (rg,ch)
// owns rows rg*16..+16 and OUTPUT COLS ch*128..+128 -> per-wave regs
// xf(32)+acc(32)~=85 unified -> 6 waves/SIMD -> 24 waves/CU (vs R1's 12,
// which was register-bound at 136 unified). Weights pre-swizzled to B-frag
// order, staged global->LDS via global_load_lds x16.

#define D_MODEL 256
#define D_HID   1024
#define MT      64               // rows per block
#define CHUNK   32               // hidden units per chunk
#define NCHUNK  (D_HID / CHUNK)  // 32
#define CHUNK_ELEMS (CHUNK * D_MODEL)  // 8192 bf16 elems = 16 KB
#define SH_STRIDE 48             // halfwords; 96 B = 6*16 -> b128-aligned rows

typedef __attribute__((ext_vector_type(8))) short short8;
typedef __attribute__((ext_vector_type(4))) float v4f;

__device__ __forceinline__ unsigned short f2bf(float f) {
  union { float f; unsigned int u; } v; v.f = f;
  unsigned int u = v.u;
  return (unsigned short)((u + 0x7FFFu + ((u >> 16) & 1u)) >> 16);  // RNE
}

__device__ __forceinline__ void async16(void* lds, const void* g) {
  __builtin_amdgcn_global_load_lds(
      (const __attribute__((address_space(1))) unsigned int*)g,
      (__attribute__((address_space(3))) unsigned int*)lds,
      16, 0, 0);
}

// ---------------- prep: mask+cast+swizzle weights into B-frag order ----------
// W1p elem offset: c*8192 + (kk*2+nf)*512 + lane*8 + j
//   holds W1eff[h = c*32 + nf*16 + (lane&15)][k = kk*32 + (lane>>4)*8 + j]
// W2p elem offset: c*8192 + nf2*512 + lane*8 + j
//   holds W2eff[n = nf2*16 + (lane&15)][h = c*32 + (lane>>4)*8 + j]
__global__ __launch_bounds__(256) void prep_weights(
    const float* __restrict__ w1, const float* __restrict__ w2,
    const int* __restrict__ mask,
    unsigned short* __restrict__ W1p, unsigned short* __restrict__ W2p)
{
  int t = blockIdx.x * 256 + threadIdx.x;   // 0..65535
  if (t < 32768) {
    int c    = t >> 10;
    int kk   = (t >> 7) & 7;
    int nf   = (t >> 6) & 1;
    int lane = t & 63;
    int h = c * 32 + nf * 16 + (lane & 15);
    int k = kk * 32 + (lane >> 4) * 8;
    const float* wp = w1 + h * 256 + k;
    const int*   mp = mask + h * 256 + k;
    short8 v;
    #pragma unroll
    for (int j = 0; j < 8; ++j) v[j] = (short)(mp[j] ? f2bf(wp[j]) : 0);
    *(short8*)(W1p + (size_t)t * 8) = v;
  } else {
    int s    = t - 32768;
    int c    = s >> 10;
    int nf2  = (s >> 6) & 15;
    int lane = s & 63;
    int n = nf2 * 16 + (lane & 15);
    int h = c * 32 + (lane >> 4) * 8;
    const float* wp = w2 + n * 1024 + h;
    short8 v;
    #pragma unroll
    for (int j = 0; j < 8; ++j)
      v[j] = (short)(mask[(h + j) * 256 + n] ? f2bf(wp[j]) : 0);
    *(short8*)(W2p + (size_t)s * 8) = v;
  }
}

// ---------------- fused main kernel ----------------
__global__ __launch_bounds__(512, 6) void ffd_fused(
    const float* __restrict__ X, const float* __restrict__ b1,
    const float* __restrict__ b2,
    const unsigned short* __restrict__ W1p, const unsigned short* __restrict__ W2p,
    float* __restrict__ Y)
{
  __shared__ alignas(16) unsigned short sW1[CHUNK_ELEMS];       // 16 KB
  __shared__ alignas(16) unsigned short sW2[CHUNK_ELEMS];       // 16 KB
  __shared__ alignas(16) unsigned short sH[4][16 * SH_STRIDE];  // 6 KB, per row-group

  const int tid  = threadIdx.x;
  const int lane = tid & 63;
  const int w    = tid >> 6;   // 0..7
  const int rg   = w >> 1;     // row-group 0..3 (16 rows each)
  const int ch   = w & 1;      // column-half (fc1 hidden half / fc2 out half)
  const int l16  = lane & 15;
  const int q    = lane >> 4;

  const long rowBase = (long)blockIdx.x * MT + rg * 16;

  // X A-fragments for this wave's 16 rows, full K=256 (32 VGPRs):
  //   xf[kk][j] = X[rowBase + l16][kk*32 + q*8 + j]
  short8 xf[8];
  {
    const float* xrow = X + (rowBase + l16) * D_MODEL;
    #pragma unroll
    for (int kk = 0; kk < 8; ++kk) {
      const float4 f0 = *(const float4*)(xrow + kk * 32 + q * 8);
      const float4 f1 = *(const float4*)(xrow + kk * 32 + q * 8 + 4);
      short8 v;
      v[0] = (short)f2bf(f0.x); v[1] = (short)f2bf(f0.y);
      v[2] = (short)f2bf(f0.z); v[3] = (short)f2bf(f0.w);
      v[4] = (short)f2bf(f1.x); v[5] = (short)f2bf(f1.y);
      v[6] = (short)f2bf(f1.z); v[7] = (short)f2bf(f1.w);
      xf[kk] = v;
    }
  }

  v4f acc[8];   // this wave: 16 rows x 128 out-cols (32 regs)
  #pragma unroll
  for (int i = 0; i < 8; ++i) acc[i] = (v4f){0.f, 0.f, 0.f, 0.f};

  #pragma unroll 1
  for (int c = 0; c < NCHUNK; ++c) {
    __syncthreads();   // prev chunk's sW/sH reads done
    {
      const unsigned short* g1 = W1p + (size_t)c * CHUNK_ELEMS + tid * 8;
      const unsigned short* g2 = W2p + (size_t)c * CHUNK_ELEMS + tid * 8;
      async16(&sW1[tid * 8], g1);
      async16(&sW1[4096 + tid * 8], g1 + 4096);
      async16(&sW2[tid * 8], g2);
      async16(&sW2[4096 + tid * 8], g2 + 4096);
    }
    const float bb = b1[c * CHUNK + ch * 16 + l16];
    __syncthreads();   // staging drained

    // fc1: H[this wave's 16 rows][hidden ch*16..+16]
    v4f hacc = (v4f){0.f, 0.f, 0.f, 0.f};
    #pragma unroll
    for (int kk = 0; kk < 8; ++kk) {
      short8 bf = *(const short8*)&sW1[(kk * 2 + ch) * 512 + lane * 8];
      hacc = __builtin_amdgcn_mfma_f32_16x16x32_bf16(xf[kk], bf, hacc, 0, 0, 0);
    }

    // bias + relu -> shared H tile for this row-group (both ch-waves fill it)
    #pragma unroll
    for (int r = 0; r < 4; ++r) {
      float v = hacc[r] + bb;
      v = v > 0.f ? v : 0.f;
      sH[rg][(q * 4 + r) * SH_STRIDE + ch * 16 + l16] = f2bf(v);
    }
    __syncthreads();   // sH complete (ch pair exchange)

    // fc2: acc[16 rows][cols ch*128..+128] += H(16x32) @ W2c^T
    short8 af = *(const short8*)&sH[rg][l16 * SH_STRIDE + q * 8];
    #pragma unroll
    for (int ntl = 0; ntl < 8; ++ntl) {
      short8 bf = *(const short8*)&sW2[(ch * 8 + ntl) * 512 + lane * 8];
      acc[ntl] = __builtin_amdgcn_mfma_f32_16x16x32_bf16(af, bf, acc[ntl], 0, 0, 0);
    }
  }

  // epilogue: + b2, store fp32
  #pragma unroll
  for (int ntl = 0; ntl < 8; ++ntl) {
    int col = ch * 128 + ntl * 16 + l16;
    float bias = b2[col];
    #pragma unroll
    for (int r = 0; r < 4; ++r) {
      long row = rowBase + q * 4 + r;
      Y[row * D_MODEL + col] = acc[ntl][r] + bias;
    }
  }
}

extern "C" void kernel_launch(void* const* d_in, const int* in_sizes, int n_in,
                              void* d_out, int out_size, void* d_ws, size_t ws_size,
                              hipStream_t stream) {
  const float* x    = (const float*)d_in[0];
  const float* w1   = (const float*)d_in[1];
  const float* b1   = (const float*)d_in[2];
  const float* w2   = (const float*)d_in[3];
  const float* b2   = (const float*)d_in[4];
  const int*   mask = (const int*)d_in[5];

  unsigned short* W1p = (unsigned short*)d_ws;          // 512 KB
  unsigned short* W2p = W1p + (size_t)D_HID * D_MODEL;  // 512 KB
  float* Y = (float*)d_out;

  prep_weights<<<256, 256, 0, stream>>>(w1, w2, mask, W1p, W2p);
  ffd_fused<<<131072 / MT, 512, 0, stream>>>(x, b1, b2, W1p, W2p, Y);
}